// Round 1
// baseline (272.827 us; speedup 1.0000x reference)
//
#include <hip/hip_runtime.h>

#define NMS_N 2048
#define NMS_B 4
#define NMS_C 16
#define NMS_T 256

__global__ __launch_bounds__(NMS_T) void nms_kernel(
    const float* __restrict__ boxes,
    const float* __restrict__ scores,
    const float* __restrict__ iou_thr_p,
    const float* __restrict__ score_thr_p,
    int K,
    int* __restrict__ out)
{
  __shared__ float s_score[NMS_N];
  __shared__ int   s_idx[NMS_N];
  __shared__ float s_x1[NMS_N], s_y1[NMS_N], s_x2[NMS_N], s_y2[NMS_N];
  __shared__ float s_area[NMS_N];
  __shared__ unsigned char s_sup[NMS_N];

  const int bc = blockIdx.x;
  const int b  = bc / NMS_C;
  const int c  = bc % NMS_C;
  const int t  = threadIdx.x;

  const float iou_thr = *iou_thr_p;
  const float sthr    = *score_thr_p;

  // ---- load scores + init ----
  const float* sc = scores + ((size_t)b * NMS_C + c) * NMS_N;
  for (int i = t; i < NMS_N; i += NMS_T) {
    s_score[i] = sc[i];
    s_idx[i]   = i;
    s_sup[i]   = 0;
  }

  // ---- bitonic sort: descending score, ties broken by ascending index ----
  // Matches jnp.argsort(-scores) (stable) because (score desc, idx asc) is a
  // total order identical to the stable-sort result.
  for (int size = 2; size <= NMS_N; size <<= 1) {
    for (int stride = size >> 1; stride > 0; stride >>= 1) {
      __syncthreads();
      for (int i = t; i < NMS_N; i += NMS_T) {
        int j = i ^ stride;
        if (j > i) {
          float si = s_score[i], sj = s_score[j];
          int   ii = s_idx[i],   ij = s_idx[j];
          // prec_ji: element j should precede element i in descending order
          bool prec_ji  = (sj > si) || (sj == si && ij < ii);
          bool ascBlock = ((i & size) == 0);
          bool doSwap   = ascBlock ? prec_ji : !prec_ji;
          if (doSwap) {
            s_score[i] = sj; s_score[j] = si;
            s_idx[i]   = ij; s_idx[j]   = ii;
          }
        }
      }
    }
  }
  __syncthreads();

  // ---- gather boxes in sorted order, fix min/max, precompute area ----
  for (int i = t; i < NMS_N; i += NMS_T) {
    int oi = s_idx[i];
    const float* bp = boxes + ((size_t)b * NMS_N + oi) * 4;
    float a0 = bp[0], a1 = bp[1], a2 = bp[2], a3 = bp[3];
    float x1 = fminf(a0, a2), x2 = fmaxf(a0, a2);
    float y1 = fminf(a1, a3), y2 = fmaxf(a1, a3);
    s_x1[i] = x1; s_y1[i] = y1; s_x2[i] = x2; s_y2[i] = y2;
    s_area[i] = (x2 - x1) * (y2 - y1);
  }

  // ---- init output rows to -1 ----
  int* orow = out + (size_t)bc * K * 3;
  for (int i = t; i < K * 3; i += NMS_T) orow[i] = -1;

  __syncthreads();

  // ---- greedy NMS ----
  int cur = 0, kept = 0;
  for (;;) {
    // uniform scan for next unsuppressed box (LDS broadcast read, no divergence)
    while (cur < NMS_N && s_sup[cur]) cur++;
    if (cur >= NMS_N || kept >= K) break;

    float kx1 = s_x1[cur], ky1 = s_y1[cur];
    float kx2 = s_x2[cur], ky2 = s_y2[cur];
    float karea = s_area[cur];

    if (t == 0) {
      // scores descending => valid outputs form a prefix; exactly the
      // reference's count = #(kept & score >= thr) trim.
      if (s_score[cur] >= sthr) {
        orow[kept * 3 + 0] = b;
        orow[kept * 3 + 1] = c;
        orow[kept * 3 + 2] = s_idx[cur];
      }
    }
    kept++;

    // parallel suppression sweep over j > cur
    for (int j = cur + 1 + t; j < NMS_N; j += NMS_T) {
      if (!s_sup[j]) {
        float ix1 = fmaxf(kx1, s_x1[j]);
        float iy1 = fmaxf(ky1, s_y1[j]);
        float ix2 = fminf(kx2, s_x2[j]);
        float iy2 = fminf(ky2, s_y2[j]);
        float iw = fmaxf(ix2 - ix1, 0.0f);
        float ih = fmaxf(iy2 - iy1, 0.0f);
        float inter = iw * ih;
        // block ffp-contract=fast from fusing (denom = a - iw*ih) into an FMA,
        // which would change rounding vs the numpy reference.
        asm volatile("" : "+v"(inter));
        float denom = karea + s_area[j] - inter;
        float iou = inter / denom;
        if (iou > iou_thr) s_sup[j] = 1;
      }
    }
    cur++;
    __syncthreads();  // sweep's s_sup writes visible to next iteration's scan
  }
}

extern "C" void kernel_launch(void* const* d_in, const int* in_sizes, int n_in,
                              void* d_out, int out_size, void* d_ws, size_t ws_size,
                              hipStream_t stream) {
  const float* boxes  = (const float*)d_in[0];
  const float* scores = (const float*)d_in[1];
  // d_in[2] = max_output_boxes_per_class (int) -- K also derivable from out_size
  const float* iou_p  = (const float*)d_in[3];
  const float* sth_p  = (const float*)d_in[4];
  int* out = (int*)d_out;

  const int K = out_size / (NMS_B * NMS_C * 3);

  hipLaunchKernelGGL(nms_kernel, dim3(NMS_B * NMS_C), dim3(NMS_T), 0, stream,
                     boxes, scores, iou_p, sth_p, K, out);
}

// Round 2
// 211.953 us; speedup vs baseline: 1.2872x; 1.2872x over previous
//
#include <hip/hip_runtime.h>

#define NN 2048
#define NT 256          // threads per block (4 waves)
#define NE 8            // elements per thread for the sort
#define NB 4
#define NC 16
#define TILE 64
#define NTILES (NN / TILE)

// strict total order: descending score, ascending index on ties
__device__ __forceinline__ bool prec(float sa, int ia, float sb, int ib) {
  return (sa > sb) || (sa == sb && ia < ib);
}

// IoU with the exact op order of the reference; asm guard blocks
// ffp-contract from fusing (ka + a - iw*ih) into an FMA.
__device__ __forceinline__ float iou_f(float kx1, float ky1, float kx2, float ky2, float ka,
                                       float x1, float y1, float x2, float y2, float a) {
  float ix1 = fmaxf(kx1, x1);
  float iy1 = fmaxf(ky1, y1);
  float ix2 = fminf(kx2, x2);
  float iy2 = fminf(ky2, y2);
  float iw = fmaxf(ix2 - ix1, 0.0f);
  float ih = fmaxf(iy2 - iy1, 0.0f);
  float inter = iw * ih;
  asm volatile("" : "+v"(inter));
  float denom = ka + a - inter;
  return inter / denom;
}

__global__ __launch_bounds__(NT) void nms_kernel(
    const float* __restrict__ boxes,
    const float* __restrict__ scores,
    const float* __restrict__ iou_thr_p,
    const float* __restrict__ score_thr_p,
    int K,
    int* __restrict__ out)
{
  __shared__ float s_score[NN];
  __shared__ int   s_sidx[NN];
  __shared__ float s_x1[NN], s_y1[NN], s_x2[NN], s_y2[NN], s_area[NN];
  __shared__ unsigned char s_sup[NN];
  __shared__ unsigned long long s_colmask[4][TILE];
  __shared__ float s_kx1[TILE], s_ky1[TILE], s_kx2[TILE], s_ky2[TILE], s_ka[TILE];
  __shared__ int s_kc, s_total;

  const int bc = blockIdx.x;
  const int b  = bc / NC;
  const int c  = bc % NC;
  const int t  = threadIdx.x;
  const int gbase = t * NE;

  const float iou_thr = *iou_thr_p;
  const float sthr    = *score_thr_p;

  // ---- load scores into registers (8 contiguous per thread) ----
  const float* sc = scores + ((size_t)b * NC + c) * NN;
  float ks[NE]; int kid[NE];
  {
    const float4* s4 = (const float4*)sc;
    float4 v0 = s4[t * 2], v1 = s4[t * 2 + 1];
    ks[0] = v0.x; ks[1] = v0.y; ks[2] = v0.z; ks[3] = v0.w;
    ks[4] = v1.x; ks[5] = v1.y; ks[6] = v1.z; ks[7] = v1.w;
    for (int k = 0; k < NE; k++) kid[k] = gbase + k;
  }

  // ---- init suppression flags, output rows, total counter ----
  for (int i = t; i < NN; i += NT) s_sup[i] = 0;
  int* orow = out + (size_t)bc * K * 3;
  for (int i = t; i < K * 3; i += NT) orow[i] = -1;
  if (t == 0) s_total = 0;

  // ---- register/shuffle bitonic sort (desc score, asc idx) ----
  // pair (g, g^d); asc block iff (g & s) == 0; final pass fully "asc" = our order.
  for (int s = 2; s <= NN; s <<= 1) {
    for (int d = s >> 1; d > 0; d >>= 1) {
      if (d >= 512) {
        // cross-wave: exchange through LDS (only 3 such passes total)
        __syncthreads();
        for (int k = 0; k < NE; k++) { s_score[gbase + k] = ks[k]; s_sidx[gbase + k] = kid[k]; }
        __syncthreads();
        const int pb = (t ^ (d >> 3)) * NE;
        const bool asc   = ((gbase & s) == 0);
        const bool lower = ((gbase & d) == 0);
        for (int k = 0; k < NE; k++) {
          float os = s_score[pb + k]; int oi = s_sidx[pb + k];
          bool mine_first = prec(ks[k], kid[k], os, oi);
          bool take_other = (asc == lower) ? !mine_first : mine_first;
          if (take_other) { ks[k] = os; kid[k] = oi; }
        }
      } else if (d >= 8) {
        // same-wave: shuffle exchange, no barriers
        const int h = d >> 3;
        const bool asc   = ((gbase & s) == 0);
        const bool lower = ((t & h) == 0);
        for (int k = 0; k < NE; k++) {
          float os = __shfl_xor(ks[k], h, 64);
          int   oi = __shfl_xor(kid[k], h, 64);
          bool mine_first = prec(ks[k], kid[k], os, oi);
          bool take_other = (asc == lower) ? !mine_first : mine_first;
          if (take_other) { ks[k] = os; kid[k] = oi; }
        }
      } else {
        // in-register within the thread's 8 elements
        for (int k = 0; k < NE; k++) {
          int kk = k ^ d;
          if (kk > k) {
            bool asc = (((gbase + k) & s) == 0);
            bool sw = asc ? prec(ks[kk], kid[kk], ks[k], kid[k])
                          : prec(ks[k], kid[k], ks[kk], kid[kk]);
            if (sw) {
              float tf = ks[k]; ks[k] = ks[kk]; ks[kk] = tf;
              int   ti = kid[k]; kid[k] = kid[kk]; kid[kk] = ti;
            }
          }
        }
      }
    }
  }

  // ---- store sorted order, gather boxes (fixed) + areas ----
  __syncthreads();
  for (int k = 0; k < NE; k++) { s_score[gbase + k] = ks[k]; s_sidx[gbase + k] = kid[k]; }
  __syncthreads();
  for (int i = t; i < NN; i += NT) {
    int oi = s_sidx[i];
    float4 v = *(const float4*)(boxes + ((size_t)b * NN + oi) * 4);
    float x1 = fminf(v.x, v.z), x2 = fmaxf(v.x, v.z);
    float y1 = fminf(v.y, v.w), y2 = fmaxf(v.y, v.w);
    s_x1[i] = x1; s_y1[i] = y1; s_x2[i] = x2; s_y2[i] = y2;
    s_area[i] = (x2 - x1) * (y2 - y1);
  }
  __syncthreads();

  // ---- tiled greedy NMS ----
  const int wv = t >> 6;    // wave id 0..3
  const int ln = t & 63;    // lane id
  for (int tile = 0; tile < NTILES; tile++) {
    const int base = tile * TILE;

    // Phase A: 64x64 upper-triangle IoU bitmask; wave wv covers rows wv*16..+15,
    // lane ln owns column j = base+ln.
    {
      unsigned long long m = 0ULL;
      const int j = base + ln;
      float jx1 = s_x1[j], jy1 = s_y1[j], jx2 = s_x2[j], jy2 = s_y2[j], ja = s_area[j];
      for (int r = 0; r < 16; r++) {
        int il = wv * 16 + r;
        if (s_sup[base + il]) continue;          // wave-uniform branch
        if (il < ln) {
          float iou = iou_f(s_x1[base + il], s_y1[base + il], s_x2[base + il],
                            s_y2[base + il], s_area[base + il],
                            jx1, jy1, jx2, jy2, ja);
          if (iou > iou_thr) m |= (1ULL << il);
        }
      }
      s_colmask[wv][ln] = m;
    }
    __syncthreads();

    // Phase B: wave 0 resolves intra-tile greedy with a 64-step ballot loop.
    if (t < 64) {
      unsigned long long m = s_colmask[0][ln] | s_colmask[1][ln] |
                             s_colmask[2][ln] | s_colmask[3][ln];
      unsigned long long alive = __ballot(s_sup[base + ln] == 0);
      for (int i = 0; i < TILE; i++) {
        if ((alive >> i) & 1ULL) {
          unsigned long long kill = __ballot((int)((m >> i) & 1ULL));
          alive &= ~kill;
        }
      }
      int total0 = s_total;
      bool kept = (alive >> ln) & 1ULL;
      int pos = __popcll(alive & ((1ULL << ln) - 1ULL));
      if (kept) {
        s_kx1[pos] = s_x1[base + ln]; s_ky1[pos] = s_y1[base + ln];
        s_kx2[pos] = s_x2[base + ln]; s_ky2[pos] = s_y2[base + ln];
        s_ka[pos]  = s_area[base + ln];
        int r = total0 + pos;
        if (r < K && s_score[base + ln] >= sthr) {
          orow[r * 3 + 0] = b;
          orow[r * 3 + 1] = c;
          orow[r * 3 + 2] = s_sidx[base + ln];
        }
      }
      if (ln == 0) {
        int kc = (int)__popcll(alive);
        s_kc = kc;
        s_total = total0 + kc;
      }
    }
    __syncthreads();

    const int total = s_total;
    const int kc    = s_kc;
    if (total >= K || tile == NTILES - 1) break;   // uniform

    // Phase C: suppress all later boxes against this tile's kept list.
    for (int j = base + TILE + t; j < NN; j += NT) {
      if (!s_sup[j]) {
        float jx1 = s_x1[j], jy1 = s_y1[j], jx2 = s_x2[j], jy2 = s_y2[j], ja = s_area[j];
        bool dead = false;
        for (int ki = 0; ki < kc; ki++) {
          float iou = iou_f(s_kx1[ki], s_ky1[ki], s_kx2[ki], s_ky2[ki], s_ka[ki],
                            jx1, jy1, jx2, jy2, ja);
          if (iou > iou_thr) { dead = true; break; }
        }
        if (dead) s_sup[j] = 1;
      }
    }
    __syncthreads();
  }
}

extern "C" void kernel_launch(void* const* d_in, const int* in_sizes, int n_in,
                              void* d_out, int out_size, void* d_ws, size_t ws_size,
                              hipStream_t stream) {
  const float* boxes  = (const float*)d_in[0];
  const float* scores = (const float*)d_in[1];
  const float* iou_p  = (const float*)d_in[3];
  const float* sth_p  = (const float*)d_in[4];
  int* out = (int*)d_out;

  const int K = out_size / (NB * NC * 3);

  hipLaunchKernelGGL(nms_kernel, dim3(NB * NC), dim3(NT), 0, stream,
                     boxes, scores, iou_p, sth_p, K, out);
}

// Round 3
// 66.056 us; speedup vs baseline: 4.1302x; 3.2087x over previous
//
#include <hip/hip_runtime.h>

#define NN 2048
#define NT 256          // threads per block (4 waves)
#define NE 8            // elements per thread for the sort
#define NB 4
#define NC 16
#define NCLS (NB * NC)
#define TILE 64
#define NTILES (NN / TILE)
#define KKEEP 176       // >= (K-1) + 64 = 163

typedef unsigned long long u64;

// key = (~orderable(score) << 32) | idx  -> ascending u64 == (score desc, idx asc)
__device__ __forceinline__ u64 make_key(float s, int idx) {
  unsigned u = __float_as_uint(s);
  u ^= (u >> 31) ? 0xFFFFFFFFu : 0x80000000u;  // ascending-orderable
  u = ~u;                                      // descending score
  return ((u64)u << 32) | (unsigned)idx;
}
__device__ __forceinline__ float key_score(u64 key) {
  unsigned u = ~(unsigned)(key >> 32);
  unsigned bits = (u >> 31) ? (u ^ 0x80000000u) : ~u;
  return __uint_as_float(bits);
}

__device__ __forceinline__ u64 shfl_xor_u64(u64 v, int h) {
  int lo = __shfl_xor((int)(unsigned)v, h, 64);
  int hi = __shfl_xor((int)(unsigned)(v >> 32), h, 64);
  return ((u64)(unsigned)hi << 32) | (unsigned)lo;
}

// IoU with the exact op order of the reference; asm guard blocks
// ffp-contract from fusing (ka + a - iw*ih) into an FMA.
__device__ __forceinline__ float iou_f(float kx1, float ky1, float kx2, float ky2, float ka,
                                       float x1, float y1, float x2, float y2, float a) {
  float ix1 = fmaxf(kx1, x1);
  float iy1 = fmaxf(ky1, y1);
  float ix2 = fminf(kx2, x2);
  float iy2 = fminf(ky2, y2);
  float iw = fmaxf(ix2 - ix1, 0.0f);
  float ih = fmaxf(iy2 - iy1, 0.0f);
  float inter = iw * ih;
  asm volatile("" : "+v"(inter));
  float denom = ka + a - inter;
  return inter / denom;
}

// ---------------- kernel 1: per-class sort + box gather ----------------
__global__ __launch_bounds__(NT) void sort_kernel(
    const float* __restrict__ boxes,
    const float* __restrict__ scores,
    float* __restrict__ wx1, float* __restrict__ wy1,
    float* __restrict__ wx2, float* __restrict__ wy2,
    float* __restrict__ wsc, int* __restrict__ widx)
{
  __shared__ u64 s_key[NN];

  const int bc = blockIdx.x;
  const int b  = bc >> 4;
  const int t  = threadIdx.x;
  const int gbase = t * NE;

  u64 key[NE];
  {
    const float4* s4 = (const float4*)(scores + (size_t)bc * NN);
    float4 v0 = s4[t * 2], v1 = s4[t * 2 + 1];
    key[0] = make_key(v0.x, gbase + 0);
    key[1] = make_key(v0.y, gbase + 1);
    key[2] = make_key(v0.z, gbase + 2);
    key[3] = make_key(v0.w, gbase + 3);
    key[4] = make_key(v1.x, gbase + 4);
    key[5] = make_key(v1.y, gbase + 5);
    key[6] = make_key(v1.z, gbase + 6);
    key[7] = make_key(v1.w, gbase + 7);
  }

  // bitonic sort, ascending u64 keys
  for (int s = 2; s <= NN; s <<= 1) {
    for (int d = s >> 1; d > 0; d >>= 1) {
      if (d >= 512) {
        // cross-wave exchange through LDS (3 passes total)
        __syncthreads();
        for (int k = 0; k < NE; k++) s_key[gbase + k] = key[k];
        __syncthreads();
        const int pb = (t ^ (d >> 3)) * NE;
        const bool asc   = ((gbase & s) == 0);
        const bool lower = ((gbase & d) == 0);
        for (int k = 0; k < NE; k++) {
          u64 o = s_key[pb + k];
          bool take = (asc == lower) ? (o < key[k]) : (o > key[k]);
          if (take) key[k] = o;
        }
      } else if (d >= 8) {
        // same-wave shuffle exchange
        const int h = d >> 3;
        const bool asc   = ((gbase & s) == 0);
        const bool lower = ((t & h) == 0);
        for (int k = 0; k < NE; k++) {
          u64 o = shfl_xor_u64(key[k], h);
          bool take = (asc == lower) ? (o < key[k]) : (o > key[k]);
          if (take) key[k] = o;
        }
      } else {
        // in-register within the thread's 8 elements
        for (int k = 0; k < NE; k++) {
          int kk = k ^ d;
          if (kk > k) {
            bool asc = (((gbase + k) & s) == 0);
            bool sw  = asc ? (key[k] > key[kk]) : (key[k] < key[kk]);
            if (sw) { u64 tmp = key[k]; key[k] = key[kk]; key[kk] = tmp; }
          }
        }
      }
    }
  }

  // gather boxes in sorted order, fix min/max, write planes
  const float* bbase = boxes + (size_t)b * NN * 4;
  const size_t obase = (size_t)bc * NN;
  for (int k = 0; k < NE; k++) {
    int g = gbase + k;
    int idx = (int)(unsigned)(key[k] & 0xFFFFFFFFu);
    float4 v = *(const float4*)(bbase + (size_t)idx * 4);
    float x1 = fminf(v.x, v.z), x2 = fmaxf(v.x, v.z);
    float y1 = fminf(v.y, v.w), y2 = fmaxf(v.y, v.w);
    wx1[obase + g] = x1; wy1[obase + g] = y1;
    wx2[obase + g] = x2; wy2[obase + g] = y2;
    wsc[obase + g] = key_score(key[k]);
    widx[obase + g] = idx;
  }
}

// ---------------- kernel 2: per-class tiled greedy NMS ----------------
__global__ __launch_bounds__(NT) void greedy_kernel(
    const float* __restrict__ wx1, const float* __restrict__ wy1,
    const float* __restrict__ wx2, const float* __restrict__ wy2,
    const float* __restrict__ wsc, const int* __restrict__ widx,
    const float* __restrict__ iou_thr_p, const float* __restrict__ score_thr_p,
    int K, int* __restrict__ out)
{
  __shared__ float s_kx1[KKEEP], s_ky1[KKEEP], s_kx2[KKEEP], s_ky2[KKEEP], s_ka[KKEEP];
  __shared__ float s_tx1[TILE], s_ty1[TILE], s_tx2[TILE], s_ty2[TILE], s_ts[TILE];
  __shared__ int   s_tidx[TILE];
  __shared__ u64   s_colmask[4][TILE];
  __shared__ u64   s_dead[4];
  __shared__ int   s_total;

  const int bc = blockIdx.x;
  const int b  = bc >> 4;
  const int c  = bc & 15;
  const int t  = threadIdx.x;
  const int wv = t >> 6;
  const int ln = t & 63;

  const float iou_thr = *iou_thr_p;
  const float sthr    = *score_thr_p;

  int* orow = out + (size_t)bc * K * 3;
  for (int i = t; i < K * 3; i += NT) orow[i] = -1;
  if (t == 0) s_total = 0;

  const size_t base0 = (size_t)bc * NN;
  __syncthreads();

  for (int tile = 0; tile < NTILES; tile++) {
    const int base = tile * TILE;

    // load tile data into LDS (each wave loads distinct arrays)
    if      (wv == 0) { s_tx1[ln] = wx1[base0 + base + ln]; s_ts[ln]   = wsc[base0 + base + ln]; }
    else if (wv == 1) { s_ty1[ln] = wy1[base0 + base + ln]; s_tidx[ln] = widx[base0 + base + ln]; }
    else if (wv == 2) { s_tx2[ln] = wx2[base0 + base + ln]; }
    else              { s_ty2[ln] = wy2[base0 + base + ln]; }
    const int kcount = s_total;       // stable: last written before previous barrier
    __syncthreads();

    // Phase B: column ln owned per-wave; intra-tile triangle rows wv*16..+15
    // plus suppression vs kept list (strided by wave).
    float jx1 = s_tx1[ln], jy1 = s_ty1[ln], jx2 = s_tx2[ln], jy2 = s_ty2[ln];
    float ja  = (jx2 - jx1) * (jy2 - jy1);   // bit-identical to reference area
    u64 m = 0ULL;
    for (int r = 0; r < 16; r++) {
      int il = wv * 16 + r;
      if (il < ln) {
        float rx1 = s_tx1[il], ry1 = s_ty1[il], rx2 = s_tx2[il], ry2 = s_ty2[il];
        float ra  = (rx2 - rx1) * (ry2 - ry1);
        float iou = iou_f(rx1, ry1, rx2, ry2, ra, jx1, jy1, jx2, jy2, ja);
        if (iou > iou_thr) m |= (1ULL << il);
      }
    }
    s_colmask[wv][ln] = m;

    bool dead = false;
    for (int ki = wv; ki < kcount; ki += 4) {
      float iou = iou_f(s_kx1[ki], s_ky1[ki], s_kx2[ki], s_ky2[ki], s_ka[ki],
                        jx1, jy1, jx2, jy2, ja);
      if (iou > iou_thr) { dead = true; break; }
    }
    s_dead[wv] = __ballot(dead);
    __syncthreads();

    // Phase C: wave 0 resolves intra-tile greedy, appends kept, writes output
    if (t < 64) {
      u64 mc = s_colmask[0][ln] | s_colmask[1][ln] | s_colmask[2][ln] | s_colmask[3][ln];
      u64 alive = ~(s_dead[0] | s_dead[1] | s_dead[2] | s_dead[3]);
      for (int i = 0; i < TILE; i++) {
        if ((alive >> i) & 1ULL) {
          u64 kill = __ballot((int)((mc >> i) & 1ULL));
          alive &= ~kill;
        }
      }
      int total0 = s_total;
      bool kept = (alive >> ln) & 1ULL;
      int pos = __popcll(alive & ((1ULL << ln) - 1ULL));
      if (kept) {
        int kpos = total0 + pos;                 // <= 99 + 63 < KKEEP
        s_kx1[kpos] = jx1; s_ky1[kpos] = jy1;
        s_kx2[kpos] = jx2; s_ky2[kpos] = jy2; s_ka[kpos] = ja;
        if (kpos < K && s_ts[ln] >= sthr) {
          orow[kpos * 3 + 0] = b;
          orow[kpos * 3 + 1] = c;
          orow[kpos * 3 + 2] = s_tidx[ln];
        }
      }
      if (ln == 0) s_total = total0 + (int)__popcll(alive);
    }
    __syncthreads();
    if (s_total >= K) break;   // uniform; stable until next Phase C
  }
}

extern "C" void kernel_launch(void* const* d_in, const int* in_sizes, int n_in,
                              void* d_out, int out_size, void* d_ws, size_t ws_size,
                              hipStream_t stream) {
  const float* boxes  = (const float*)d_in[0];
  const float* scores = (const float*)d_in[1];
  const float* iou_p  = (const float*)d_in[3];
  const float* sth_p  = (const float*)d_in[4];
  int* out = (int*)d_out;

  const int K = out_size / (NCLS * 3);
  const size_t plane = (size_t)NCLS * NN;

  float* w   = (float*)d_ws;
  float* wx1 = w + 0 * plane;
  float* wy1 = w + 1 * plane;
  float* wx2 = w + 2 * plane;
  float* wy2 = w + 3 * plane;
  float* wsc = w + 4 * plane;
  int*  widx = (int*)(w + 5 * plane);

  hipLaunchKernelGGL(sort_kernel, dim3(NCLS), dim3(NT), 0, stream,
                     boxes, scores, wx1, wy1, wx2, wy2, wsc, widx);
  hipLaunchKernelGGL(greedy_kernel, dim3(NCLS), dim3(NT), 0, stream,
                     wx1, wy1, wx2, wy2, wsc, widx, iou_p, sth_p, K, out);
}

// Round 4
// 53.169 us; speedup vs baseline: 5.1313x; 1.2424x over previous
//
#include <hip/hip_runtime.h>

#define NN 2048
#define NT 256          // threads per block (4 waves)
#define NB 4
#define NC 16
#define NCLS (NB * NC)
#define CHUNKS 8        // rank blocks per class
#define TILE 64
#define NTILES (NN / TILE)
#define KKEEP 176       // >= (K-1) + 64 = 163

typedef unsigned long long u64;

// key = (~orderable(score) << 32) | idx  -> ascending u64 == (score desc, idx asc)
__device__ __forceinline__ u64 make_key(float s, int idx) {
  unsigned u = __float_as_uint(s);
  u ^= (u >> 31) ? 0xFFFFFFFFu : 0x80000000u;  // ascending-orderable
  u = ~u;                                      // descending score
  return ((u64)u << 32) | (unsigned)idx;
}
__device__ __forceinline__ float key_score(u64 key) {
  unsigned u = ~(unsigned)(key >> 32);
  unsigned bits = (u >> 31) ? (u ^ 0x80000000u) : ~u;
  return __uint_as_float(bits);
}

// IoU with the exact op order of the reference; asm guard blocks
// ffp-contract from fusing (ka + a - iw*ih) into an FMA.
__device__ __forceinline__ float iou_f(float kx1, float ky1, float kx2, float ky2, float ka,
                                       float x1, float y1, float x2, float y2, float a) {
  float ix1 = fmaxf(kx1, x1);
  float iy1 = fmaxf(ky1, y1);
  float ix2 = fminf(kx2, x2);
  float iy2 = fminf(ky2, y2);
  float iw = fmaxf(ix2 - ix1, 0.0f);
  float ih = fmaxf(iy2 - iy1, 0.0f);
  float inter = iw * ih;
  asm volatile("" : "+v"(inter));
  float denom = ka + a - inter;
  return inter / denom;
}

// ---------------- kernel 1: rank sort (depth-1, O(N^2) compares) ----------------
// 512 blocks = 64 classes x 8 chunks; each block ranks 256 elements vs all 2048.
__global__ __launch_bounds__(NT) void rank_kernel(
    const float* __restrict__ boxes,
    const float* __restrict__ scores,
    float* __restrict__ wx1, float* __restrict__ wy1,
    float* __restrict__ wx2, float* __restrict__ wy2,
    float* __restrict__ wsc, int* __restrict__ widx)
{
  __shared__ u64 s_key[NN];

  const int blk   = blockIdx.x;
  const int bc    = blk >> 3;       // class id 0..63
  const int chunk = blk & 7;
  const int b     = bc >> 4;        // batch
  const int t     = threadIdx.x;

  // stage all 2048 keys of this class into LDS (8 per thread)
  {
    const float4* s4 = (const float4*)(scores + (size_t)bc * NN);
    float4 v0 = s4[t * 2], v1 = s4[t * 2 + 1];
    const int g = t * 8;
    s_key[g + 0] = make_key(v0.x, g + 0);
    s_key[g + 1] = make_key(v0.y, g + 1);
    s_key[g + 2] = make_key(v0.z, g + 2);
    s_key[g + 3] = make_key(v0.w, g + 3);
    s_key[g + 4] = make_key(v1.x, g + 4);
    s_key[g + 5] = make_key(v1.y, g + 5);
    s_key[g + 6] = make_key(v1.z, g + 6);
    s_key[g + 7] = make_key(v1.w, g + 7);
  }
  __syncthreads();

  const int i = chunk * NT + t;
  const u64 my = s_key[i];

  // rank = # keys strictly less than mine (keys unique via idx)
  int r0 = 0, r1 = 0, r2 = 0, r3 = 0;
#pragma unroll 4
  for (int j = 0; j < NN; j += 4) {
    r0 += (s_key[j + 0] < my) ? 1 : 0;
    r1 += (s_key[j + 1] < my) ? 1 : 0;
    r2 += (s_key[j + 2] < my) ? 1 : 0;
    r3 += (s_key[j + 3] < my) ? 1 : 0;
  }
  const int rank = r0 + r1 + r2 + r3;

  // gather my box, fix min/max, scatter to sorted position
  const int idx = (int)(unsigned)(my & 0xFFFFFFFFu);
  float4 v = *(const float4*)(boxes + ((size_t)b * NN + idx) * 4);
  float x1 = fminf(v.x, v.z), x2 = fmaxf(v.x, v.z);
  float y1 = fminf(v.y, v.w), y2 = fmaxf(v.y, v.w);

  const size_t o = (size_t)bc * NN + rank;
  wx1[o] = x1; wy1[o] = y1;
  wx2[o] = x2; wy2[o] = y2;
  wsc[o] = key_score(my);
  widx[o] = idx;
}

// ---------------- kernel 2: per-class tiled greedy NMS ----------------
__global__ __launch_bounds__(NT) void greedy_kernel(
    const float* __restrict__ wx1, const float* __restrict__ wy1,
    const float* __restrict__ wx2, const float* __restrict__ wy2,
    const float* __restrict__ wsc, const int* __restrict__ widx,
    const float* __restrict__ iou_thr_p, const float* __restrict__ score_thr_p,
    int K, int* __restrict__ out)
{
  __shared__ float s_kx1[KKEEP], s_ky1[KKEEP], s_kx2[KKEEP], s_ky2[KKEEP], s_ka[KKEEP];
  __shared__ float s_tx1[TILE], s_ty1[TILE], s_tx2[TILE], s_ty2[TILE], s_ts[TILE];
  __shared__ int   s_tidx[TILE];
  __shared__ u64   s_colmask[4][TILE];
  __shared__ u64   s_dead[4];
  __shared__ int   s_total;

  const int bc = blockIdx.x;
  const int b  = bc >> 4;
  const int c  = bc & 15;
  const int t  = threadIdx.x;
  const int wv = t >> 6;
  const int ln = t & 63;

  const float iou_thr = *iou_thr_p;
  const float sthr    = *score_thr_p;

  int* orow = out + (size_t)bc * K * 3;
  for (int i = t; i < K * 3; i += NT) orow[i] = -1;
  if (t == 0) s_total = 0;

  const size_t base0 = (size_t)bc * NN;
  __syncthreads();

  for (int tile = 0; tile < NTILES; tile++) {
    const int base = tile * TILE;

    // load tile data into LDS (each wave loads distinct arrays)
    if      (wv == 0) { s_tx1[ln] = wx1[base0 + base + ln]; s_ts[ln]   = wsc[base0 + base + ln]; }
    else if (wv == 1) { s_ty1[ln] = wy1[base0 + base + ln]; s_tidx[ln] = widx[base0 + base + ln]; }
    else if (wv == 2) { s_tx2[ln] = wx2[base0 + base + ln]; }
    else              { s_ty2[ln] = wy2[base0 + base + ln]; }
    const int kcount = s_total;       // stable: last written before previous barrier
    __syncthreads();

    // Phase B: column ln owned per-wave; intra-tile triangle rows wv*16..+15
    // plus suppression vs kept list (strided by wave).
    float jx1 = s_tx1[ln], jy1 = s_ty1[ln], jx2 = s_tx2[ln], jy2 = s_ty2[ln];
    float ja  = (jx2 - jx1) * (jy2 - jy1);   // bit-identical to reference area
    u64 m = 0ULL;
    for (int r = 0; r < 16; r++) {
      int il = wv * 16 + r;
      if (il < ln) {
        float rx1 = s_tx1[il], ry1 = s_ty1[il], rx2 = s_tx2[il], ry2 = s_ty2[il];
        float ra  = (rx2 - rx1) * (ry2 - ry1);
        float iou = iou_f(rx1, ry1, rx2, ry2, ra, jx1, jy1, jx2, jy2, ja);
        if (iou > iou_thr) m |= (1ULL << il);
      }
    }
    s_colmask[wv][ln] = m;

    bool dead = false;
    for (int ki = wv; ki < kcount; ki += 4) {
      float iou = iou_f(s_kx1[ki], s_ky1[ki], s_kx2[ki], s_ky2[ki], s_ka[ki],
                        jx1, jy1, jx2, jy2, ja);
      if (iou > iou_thr) { dead = true; break; }
    }
    s_dead[wv] = __ballot(dead);
    __syncthreads();

    // Phase C: wave 0 resolves intra-tile greedy, appends kept, writes output
    if (t < 64) {
      u64 mc = s_colmask[0][ln] | s_colmask[1][ln] | s_colmask[2][ln] | s_colmask[3][ln];
      u64 alive = ~(s_dead[0] | s_dead[1] | s_dead[2] | s_dead[3]);
      for (int i = 0; i < TILE; i++) {
        if ((alive >> i) & 1ULL) {
          u64 kill = __ballot((int)((mc >> i) & 1ULL));
          alive &= ~kill;
        }
      }
      int total0 = s_total;
      bool kept = (alive >> ln) & 1ULL;
      int pos = __popcll(alive & ((1ULL << ln) - 1ULL));
      if (kept) {
        int kpos = total0 + pos;                 // <= 99 + 63 < KKEEP
        s_kx1[kpos] = jx1; s_ky1[kpos] = jy1;
        s_kx2[kpos] = jx2; s_ky2[kpos] = jy2; s_ka[kpos] = ja;
        if (kpos < K && s_ts[ln] >= sthr) {
          orow[kpos * 3 + 0] = b;
          orow[kpos * 3 + 1] = c;
          orow[kpos * 3 + 2] = s_tidx[ln];
        }
      }
      if (ln == 0) s_total = total0 + (int)__popcll(alive);
    }
    __syncthreads();
    if (s_total >= K) break;   // uniform; stable until next Phase C
  }
}

extern "C" void kernel_launch(void* const* d_in, const int* in_sizes, int n_in,
                              void* d_out, int out_size, void* d_ws, size_t ws_size,
                              hipStream_t stream) {
  const float* boxes  = (const float*)d_in[0];
  const float* scores = (const float*)d_in[1];
  const float* iou_p  = (const float*)d_in[3];
  const float* sth_p  = (const float*)d_in[4];
  int* out = (int*)d_out;

  const int K = out_size / (NCLS * 3);
  const size_t plane = (size_t)NCLS * NN;

  float* w   = (float*)d_ws;
  float* wx1 = w + 0 * plane;
  float* wy1 = w + 1 * plane;
  float* wx2 = w + 2 * plane;
  float* wy2 = w + 3 * plane;
  float* wsc = w + 4 * plane;
  int*  widx = (int*)(w + 5 * plane);

  hipLaunchKernelGGL(rank_kernel, dim3(NCLS * CHUNKS), dim3(NT), 0, stream,
                     boxes, scores, wx1, wy1, wx2, wy2, wsc, widx);
  hipLaunchKernelGGL(greedy_kernel, dim3(NCLS), dim3(NT), 0, stream,
                     wx1, wy1, wx2, wy2, wsc, widx, iou_p, sth_p, K, out);
}